// Round 2
// baseline (267.215 us; speedup 1.0000x reference)
//
#include <hip/hip_runtime.h>

// PointPillars scatter: features (4,64,12000) f32 + int32 (x,y) indices
// -> pseudo image (4,64,440,500) f32, zeros elsewhere, numpy last-write-wins
// on duplicate cells (largest p wins).

#define BS 4
#define NC 64
#define NP 12000
#define NX 500
#define NY 440

// Pass 1: winner[b,y,x] = max p that scatters into this cell (-1 = empty).
__global__ void winner_kernel(const int* __restrict__ xidx,
                              const int* __restrict__ yidx,
                              int* __restrict__ winner) {
    int i = blockIdx.x * blockDim.x + threadIdx.x;   // i = b*NP + p
    if (i >= BS * NP) return;
    int b = i / NP;
    int p = i - b * NP;
    int xv = xidx[i];
    int yv = yidx[i];
    xv = min(max(xv, 0), NX - 1);
    yv = min(max(yv, 0), NY - 1);
    atomicMax(&winner[b * (NY * NX) + yv * NX + xv], p);
}

// Pass 2 (fused zero-fill + scatter-as-gather): one float4 per thread over
// the entire output. Coalesced 16B writes; int4 winner loads (NX=500 is a
// multiple of 4 so rows stay 16B-aligned); feature gathers hit a 48KB
// per-(b,c) row -> L1/L2 resident.
__global__ void fill_kernel(const float* __restrict__ feat,
                            const int* __restrict__ winner,
                            float4* __restrict__ out) {
    const int X4   = NX / 4;                 // 125
    const int TOT4 = BS * NC * NY * X4;      // 14,080,000
    int idx4 = blockIdx.x * blockDim.x + threadIdx.x;
    if (idx4 >= TOT4) return;
    int x4  = idx4 % X4;
    int rem = idx4 / X4;
    int y   = rem % NY;
    int bc  = rem / NY;                      // b*NC + c
    int c   = bc % NC;
    int b   = bc / NC;

    const int4 w = *reinterpret_cast<const int4*>(
        &winner[(b * NY + y) * NX + x4 * 4]);
    const float* fb = feat + (size_t)(b * NC + c) * NP;

    float4 o;
    o.x = (w.x >= 0) ? fb[w.x] : 0.0f;
    o.y = (w.y >= 0) ? fb[w.y] : 0.0f;
    o.z = (w.z >= 0) ? fb[w.z] : 0.0f;
    o.w = (w.w >= 0) ? fb[w.w] : 0.0f;
    out[idx4] = o;
}

extern "C" void kernel_launch(void* const* d_in, const int* in_sizes, int n_in,
                              void* d_out, int out_size, void* d_ws, size_t ws_size,
                              hipStream_t stream) {
    const float* feat = (const float*)d_in[0];
    const int*   xidx = (const int*)d_in[1];   // harness delivers integer inputs as int32
    const int*   yidx = (const int*)d_in[2];
    int*   winner = (int*)d_ws;                // 4*440*500*4 = 3.52 MB scratch
    float* out    = (float*)d_out;

    // winner := -1 everywhere (ws is re-poisoned to 0xAA before every call)
    hipMemsetAsync(winner, 0xFF, (size_t)BS * NY * NX * sizeof(int), stream);

    winner_kernel<<<(BS * NP + 255) / 256, 256, 0, stream>>>(xidx, yidx, winner);

    const int TOT4 = BS * NC * NY * (NX / 4);
    fill_kernel<<<(TOT4 + 255) / 256, 256, 0, stream>>>(
        feat, winner, (float4*)out);
}

// Round 3
// 267.036 us; speedup vs baseline: 1.0007x; 1.0007x over previous
//
#include <hip/hip_runtime.h>

// PointPillars scatter: features (4,64,12000) f32 + int32 (x,y) indices
// -> pseudo image (4,64,440,500) f32, zeros elsewhere, numpy last-write-wins
// on duplicate cells (largest p wins).

#define BS 4
#define NC 64
#define NP 12000
#define NX 500
#define NY 440
#define X4 (NX / 4)        // 125
#define CG 4               // channel groups
#define CPG (NC / CG)      // 16 channels per group

// Pass 1: winner[b,y,x] = max p that scatters into this cell (-1 = empty).
__global__ void winner_kernel(const int* __restrict__ xidx,
                              const int* __restrict__ yidx,
                              int* __restrict__ winner) {
    int i = blockIdx.x * blockDim.x + threadIdx.x;   // i = b*NP + p
    if (i >= BS * NP) return;
    int b = i / NP;
    int p = i - b * NP;
    int xv = min(max(xidx[i], 0), NX - 1);
    int yv = min(max(yidx[i], 0), NY - 1);
    atomicMax(&winner[b * (NY * NX) + yv * NX + xv], p);
}

// Pass 2: thread = (b, cgroup, y, x4). Loads winner int4 ONCE, then writes
// 16 channels' float4 for that quad. Gathers are unmasked-clamped
// (fb[max(w,0)] is always valid; w<0 lanes all broadcast-read fb[0]) +
// cndmask — no exec-mask branch dance. 16 coalesced float4 stores/thread.
__global__ void fill_kernel(const float* __restrict__ feat,
                            const int* __restrict__ winner,
                            float4* __restrict__ out) {
    const int TOT = BS * CG * NY * X4;               // 880,000
    int t = blockIdx.x * blockDim.x + threadIdx.x;
    if (t >= TOT) return;
    int x4 = t % X4;
    int r  = t / X4;
    int y  = r % NY;
    int bg = r / NY;                                  // b*CG + g
    int g  = bg % CG;
    int b  = bg / CG;

    const int4 w = reinterpret_cast<const int4*>(winner)[(b * NY + y) * X4 + x4];
    const int ix = max(w.x, 0), iy = max(w.y, 0), iz = max(w.z, 0), iw = max(w.w, 0);

    const float* fb = feat + (size_t)(b * NC + g * CPG) * NP;
    float4* o = out + ((size_t)(b * NC + g * CPG) * NY + y) * X4 + x4;

#pragma unroll
    for (int cc = 0; cc < CPG; ++cc) {
        float4 v;
        v.x = (w.x >= 0) ? fb[ix] : 0.0f;
        v.y = (w.y >= 0) ? fb[iy] : 0.0f;
        v.z = (w.z >= 0) ? fb[iz] : 0.0f;
        v.w = (w.w >= 0) ? fb[iw] : 0.0f;
        *o = v;
        fb += NP;
        o  += (size_t)NY * X4;
    }
}

extern "C" void kernel_launch(void* const* d_in, const int* in_sizes, int n_in,
                              void* d_out, int out_size, void* d_ws, size_t ws_size,
                              hipStream_t stream) {
    const float* feat = (const float*)d_in[0];
    const int*   xidx = (const int*)d_in[1];   // integer inputs arrive as int32
    const int*   yidx = (const int*)d_in[2];
    int*   winner = (int*)d_ws;                // 4*440*500*4 = 3.52 MB scratch
    float* out    = (float*)d_out;

    // winner := -1 everywhere (ws is re-poisoned to 0xAA before every call)
    hipMemsetAsync(winner, 0xFF, (size_t)BS * NY * NX * sizeof(int), stream);

    winner_kernel<<<(BS * NP + 255) / 256, 256, 0, stream>>>(xidx, yidx, winner);

    const int TOT = BS * CG * NY * X4;         // 880,000 threads
    fill_kernel<<<(TOT + 255) / 256, 256, 0, stream>>>(
        feat, winner, (float4*)out);
}